// Round 3
// baseline (94.572 us; speedup 1.0000x reference)
//
#include <hip/hip_runtime.h>
#include <math.h>

typedef __attribute__((ext_vector_type(8))) short short8;
typedef __attribute__((ext_vector_type(4))) float f32x4;
typedef __attribute__((ext_vector_type(4))) unsigned short u16x4;
typedef __attribute__((ext_vector_type(8))) unsigned short u16x8;

#define TAUF 32.0f

// LDS layout per double-buffer half (conflict-free [k-granule][row] layout):
constexpr int A_HI   = 0;       // 4 g x 64 rows x 16B = 4096 B
constexpr int A_LO   = 4096;    // 4096 B
constexpr int B_HI   = 8192;    // 4 g x 192 cols x 16B = 12288 B
constexpr int B_LO   = 20480;   // 12288 B
constexpr int BUF_SZ = 32768;
constexpr int CSTR   = 196;     // epilogue C row stride (floats)

// ---------------------------------------------------------------------------
// Kernel 1: PR[blk] = memory[dm] . W  (blk<90: W_topic ; 90..179: W_domain),
// emitted as split-bf16 planes PRhi/PRlo [192][768]; rows 180..191 zeroed.
// grid 192, block 192: thread t owns 4 consecutive cols (float4 W loads).
// ---------------------------------------------------------------------------
__global__ __launch_bounds__(192) void precompute_pr(
    const float* __restrict__ Wt, const float* __restrict__ Wd,
    const float* __restrict__ mem, unsigned short* __restrict__ PRhi,
    unsigned short* __restrict__ PRlo) {
  int blk = blockIdx.x, t = threadIdx.x;
  int i0 = t * 4;
  if (blk >= 180) {
    u16x4 z = {0, 0, 0, 0};
    *(u16x4*)&PRhi[blk * 768 + i0] = z;
    *(u16x4*)&PRlo[blk * 768 + i0] = z;
    return;
  }
  __shared__ float mlds[256];
  const float* W = (blk >= 90) ? Wd : Wt;
  int dm = (blk >= 90) ? blk - 90 : blk;
  for (int i = t; i < 256; i += 192) mlds[i] = mem[dm * 256 + i];
  __syncthreads();
  float ax = 0.f, ay = 0.f, az = 0.f, aw = 0.f;
  #pragma unroll 8
  for (int e = 0; e < 256; ++e) {
    float m = mlds[e];
    float4 w = *(const float4*)&W[e * 768 + i0];
    ax += m * w.x; ay += m * w.y; az += m * w.z; aw += m * w.w;
  }
  float xs[4] = {ax, ay, az, aw};
  u16x4 hi, lo;
  #pragma unroll
  for (int e = 0; e < 4; ++e) {
    unsigned int bu = __float_as_uint(xs[e]);
    hi[e] = (unsigned short)(bu >> 16);
    float hf = __uint_as_float(bu & 0xffff0000u);
    lo[e] = (unsigned short)(__float_as_uint(xs[e] - hf) >> 16);
  }
  *(u16x4*)&PRhi[blk * 768 + i0] = hi;
  *(u16x4*)&PRlo[blk * 768 + i0] = lo;
}

// ---------------------------------------------------------------------------
// Kernel 2: fused split-bf16 MFMA GEMM [64 rows x 192 cols x K=768] +
// row L2-norm + double softmax. 256 threads = 4 waves; wave (rg,cg) owns
// 32 rows (2 MFMA rowtiles) x 96 cols (6 coltiles). 69 KB LDS -> 2 blk/CU.
// ---------------------------------------------------------------------------
__global__ __launch_bounds__(256, 2) void fused_mfma(
    const float* __restrict__ feat, const unsigned short* __restrict__ PRhi,
    const unsigned short* __restrict__ PRlo, float* __restrict__ out) {
  __shared__ f32x4 smemv[4096];   // 65536 B: 2x32768 buffers; reused for C
  __shared__ float ssql[256];
  __shared__ float invn[64];
  __shared__ float sarr[576];
  char* smem = (char*)smemv;

  const int t    = threadIdx.x;
  const int lane = t & 63;
  const int wid  = t >> 6;        // 0..3
  const int rg   = wid >> 1;      // 0..1: rows rg*32..+31
  const int cg   = wid & 1;       // 0..1: cols cg*96..+95
  const int b0   = blockIdx.x * 64;

  // ---- A staging map: thread t -> row t&63, k-granule g=t>>6 (8 floats)
  const int arow = t & 63;
  const int ag   = t >> 6;
  const float* gA = feat + (size_t)(b0 + arow) * 768 + ag * 8;
  const int awr  = ag * 1024 + arow * 16;   // byte offset in A plane

  // ---- B DMA: 24 instrs/ktile (2 planes x 4 g x 3 col-chunks), 6 per wave
  const int iid = wid * 6;

  f32x4 acc0[6], acc1[6];
  #pragma unroll
  for (int j = 0; j < 6; ++j) {
    acc0[j] = (f32x4){0.f, 0.f, 0.f, 0.f};
    acc1[j] = (f32x4){0.f, 0.f, 0.f, 0.f};
  }
  float ssq = 0.f;

  auto issueB = [&](int kt, int bb) {
    #pragma unroll
    for (int u = 0; u < 6; ++u) {
      int i   = iid + u;
      int pl  = i / 12;            // 0: hi plane, 1: lo plane (wave-uniform)
      int idx = i - pl * 12;
      int g   = idx & 3;           // k-granule
      int c0  = (idx >> 2) << 6;   // col chunk base (0,64,128)
      const unsigned short* basep = pl ? PRlo : PRhi;
      const char* gg = (const char*)basep + (size_t)(c0 + lane) * 1536 +
                       kt * 64 + g * 16;
      char* l = smem + bb * BUF_SZ + (pl ? B_LO : B_HI) + g * 3072 + c0 * 16;
      __builtin_amdgcn_global_load_lds((const unsigned int*)gg,
                                       (unsigned int*)l, 16, 0, 0);
    }
  };

  // convert 8 fp32 -> split bf16 hi/lo (16B each), accumulate ssq
  auto cvt8 = [&](float4 a, float4 b, char* dhi, char* dlo) {
    float xs[8] = {a.x, a.y, a.z, a.w, b.x, b.y, b.z, b.w};
    u16x8 hi, lo;
    #pragma unroll
    for (int e = 0; e < 8; ++e) {
      float x = xs[e];
      ssq += x * x;
      unsigned int bu = __float_as_uint(x);
      hi[e] = (unsigned short)(bu >> 16);
      float hf = __uint_as_float(bu & 0xffff0000u);
      lo[e] = (unsigned short)(__float_as_uint(x - hf) >> 16);
    }
    *(u16x8*)dhi = hi;
    *(u16x8*)dlo = lo;
  };

  auto domfma = [&](int bb) {
    char* base = smem + bb * BUF_SZ;
    const int la = ((lane >> 4) << 10) | ((lane & 15) << 4);  // g*1024+r*16
    short8 ah0 = *(const short8*)(base + A_HI + rg * 512 + la);
    short8 ah1 = *(const short8*)(base + A_HI + rg * 512 + 256 + la);
    short8 al0 = *(const short8*)(base + A_LO + rg * 512 + la);
    short8 al1 = *(const short8*)(base + A_LO + rg * 512 + 256 + la);
    const int lb = (lane >> 4) * 3072 + cg * 1536 + ((lane & 15) << 4);
    #pragma unroll
    for (int j = 0; j < 6; ++j) {
      short8 bh = *(const short8*)(base + B_HI + lb + j * 256);
      short8 bl = *(const short8*)(base + B_LO + lb + j * 256);
      acc0[j] = __builtin_amdgcn_mfma_f32_16x16x32_bf16(ah0, bh, acc0[j], 0, 0, 0);
      acc0[j] = __builtin_amdgcn_mfma_f32_16x16x32_bf16(al0, bh, acc0[j], 0, 0, 0);
      acc0[j] = __builtin_amdgcn_mfma_f32_16x16x32_bf16(ah0, bl, acc0[j], 0, 0, 0);
      acc1[j] = __builtin_amdgcn_mfma_f32_16x16x32_bf16(ah1, bh, acc1[j], 0, 0, 0);
      acc1[j] = __builtin_amdgcn_mfma_f32_16x16x32_bf16(al1, bh, acc1[j], 0, 0, 0);
      acc1[j] = __builtin_amdgcn_mfma_f32_16x16x32_bf16(ah1, bl, acc1[j], 0, 0, 0);
    }
  };

  // ---- prologue: stage kt=0 into buf0, prefetch A(1) into regs
  float4 sa0 = *(const float4*)gA;
  float4 sa1 = *(const float4*)(gA + 4);
  issueB(0, 0);
  cvt8(sa0, sa1, smem + A_HI + awr, smem + A_LO + awr);
  float4 sb0 = *(const float4*)(gA + 32);
  float4 sb1 = *(const float4*)(gA + 36);
  __syncthreads();

  // ---- main loop: 2 ktiles per iteration (buffer parity compile-time)
  for (int kp = 0; kp < 11; ++kp) {
    int kt = 2 * kp;
    issueB(kt + 1, 1);
    cvt8(sb0, sb1, smem + BUF_SZ + A_HI + awr, smem + BUF_SZ + A_LO + awr);
    sa0 = *(const float4*)(gA + (kt + 2) * 32);
    sa1 = *(const float4*)(gA + (kt + 2) * 32 + 4);
    domfma(0);
    __syncthreads();
    issueB(kt + 2, 0);
    cvt8(sa0, sa1, smem + A_HI + awr, smem + A_LO + awr);
    sb0 = *(const float4*)(gA + (kt + 3) * 32);
    sb1 = *(const float4*)(gA + (kt + 3) * 32 + 4);
    domfma(1);
    __syncthreads();
  }
  // tail: kt=22 (buf0) stages kt=23 -> buf1, then compute buf1
  issueB(23, 1);
  cvt8(sb0, sb1, smem + BUF_SZ + A_HI + awr, smem + BUF_SZ + A_LO + awr);
  domfma(0);
  __syncthreads();
  domfma(1);

  // ---- row L2-norm: per-thread partial (one g-chunk of one row) -> LDS
  ssql[t] = ssq;
  __syncthreads();   // also: all MFMA reads done -> buffers reusable for C
  if (t < 64)
    invn[t] = rsqrtf(ssql[t] + ssql[t + 64] + ssql[t + 128] + ssql[t + 192]);
  __syncthreads();

  // ---- write scaled C (q|r) to LDS
  float* Clds = (float*)smem;
  #pragma unroll
  for (int rt = 0; rt < 2; ++rt) {
    int rbase = rg * 32 + rt * 16 + ((lane >> 4) << 2);
    #pragma unroll
    for (int j = 0; j < 6; ++j) {
      int col = cg * 96 + j * 16 + (lane & 15);
      f32x4 v = rt ? acc1[j] : acc0[j];
      #pragma unroll
      for (int jj = 0; jj < 4; ++jj)
        Clds[(rbase + jj) * CSTR + col] = v[jj] * invn[rbase + jj];
    }
  }
  __syncthreads();

  // ---- per (row,d): softmax over m, dot with r
  for (int pid = t; pid < 576; pid += 256) {
    int row = pid / 9, d = pid - row * 9;
    const float* qp = Clds + row * CSTR + d * 10;
    const float* rp = qp + 90;
    float mx = qp[0];
    #pragma unroll
    for (int m = 1; m < 10; ++m) mx = fmaxf(mx, qp[m]);
    float s = 0.f, val = 0.f;
    #pragma unroll
    for (int m = 0; m < 10; ++m) {
      float e = __expf(TAUF * (qp[m] - mx));
      s += e;
      val += e * rp[m];
    }
    sarr[pid] = val / s;
  }
  __syncthreads();

  // ---- per row: softmax over d, write out
  if (t < 64) {
    float v[9];
    #pragma unroll
    for (int d = 0; d < 9; ++d) v[d] = sarr[t * 9 + d];
    float mx = v[0];
    #pragma unroll
    for (int d = 1; d < 9; ++d) mx = fmaxf(mx, v[d]);
    float s = 0.f;
    float e[9];
    #pragma unroll
    for (int d = 0; d < 9; ++d) {
      e[d] = __expf(TAUF * (v[d] - mx));
      s += e[d];
    }
    float is = 1.f / s;
    #pragma unroll
    for (int d = 0; d < 9; ++d)
      out[(size_t)(b0 + t) * 9 + d] = e[d] * is;
  }
}

extern "C" void kernel_launch(void* const* d_in, const int* in_sizes, int n_in,
                              void* d_out, int out_size, void* d_ws, size_t ws_size,
                              hipStream_t stream) {
  const float* feat = (const float*)d_in[0];
  // d_in[1] = category (unused by forward math)
  const float* Wt  = (const float*)d_in[2];
  const float* Wd  = (const float*)d_in[3];
  const float* mem = (const float*)d_in[4];
  float* outp = (float*)d_out;

  unsigned short* PRhi = (unsigned short*)d_ws;   // [192][768] bf16
  unsigned short* PRlo = PRhi + 192 * 768;        // [192][768] bf16

  precompute_pr<<<192, 192, 0, stream>>>(Wt, Wd, mem, PRhi, PRlo);
  const int B = in_sizes[1];   // 32768
  fused_mfma<<<B / 64, 256, 0, stream>>>(feat, PRhi, PRlo, outp);
}

// Round 4
// 68.218 us; speedup vs baseline: 1.3863x; 1.3863x over previous
//
#include <hip/hip_runtime.h>
#include <math.h>

typedef __attribute__((ext_vector_type(8))) short short8;
typedef __attribute__((ext_vector_type(4))) float f32x4;
typedef __attribute__((ext_vector_type(8))) unsigned short u16x8;

#define TAUF 32.0f

// LDS: two B double-buffer halves; C epilogue tile overlays the same space.
constexpr int B_LO_OFF = 12288;  // lo plane offset within a buffer half
constexpr int BUF_SZ   = 24576;  // one half: 192 cols x 32 k x 2 planes x 2B
constexpr int CSTR     = 196;    // epilogue C row stride (floats)

// ---------------------------------------------------------------------------
// Kernel 1: PR rows = memory[dm] . W  (rows 0..89: W_topic; 90..179: W_domain)
// as split-bf16 planes PRhi/PRlo [192][768]; rows 180..191 zeroed.
// grid 96 x 768 threads: block g owns PR rows 2g, 2g+1; thread t owns col t.
// ---------------------------------------------------------------------------
__global__ __launch_bounds__(768) void precompute_pr(
    const float* __restrict__ Wt, const float* __restrict__ Wd,
    const float* __restrict__ mem, unsigned short* __restrict__ PRhi,
    unsigned short* __restrict__ PRlo) {
  int g = blockIdx.x, t = threadIdx.x;
  int r0 = g * 2;
  if (r0 >= 180) {
    PRhi[(size_t)r0 * 768 + t] = 0;
    PRlo[(size_t)r0 * 768 + t] = 0;
    PRhi[(size_t)(r0 + 1) * 768 + t] = 0;
    PRlo[(size_t)(r0 + 1) * 768 + t] = 0;
    return;
  }
  __shared__ float mlds[512];
  const float* W = (r0 >= 90) ? Wd : Wt;
  int dm0 = (r0 >= 90) ? r0 - 90 : r0;
  if (t < 512) mlds[t] = mem[(size_t)dm0 * 256 + t];
  __syncthreads();
  float a0 = 0.f, a1 = 0.f;
  #pragma unroll 8
  for (int e = 0; e < 256; ++e) {
    float w = W[(size_t)e * 768 + t];
    a0 += mlds[e] * w;
    a1 += mlds[256 + e] * w;
  }
  float xs[2] = {a0, a1};
  #pragma unroll
  for (int rr = 0; rr < 2; ++rr) {
    unsigned int bu = __float_as_uint(xs[rr]);
    unsigned short hi = (unsigned short)(bu >> 16);
    float hf = __uint_as_float(bu & 0xffff0000u);
    unsigned short lo = (unsigned short)(__float_as_uint(xs[rr] - hf) >> 16);
    PRhi[(size_t)(r0 + rr) * 768 + t] = hi;
    PRlo[(size_t)(r0 + rr) * 768 + t] = lo;
  }
}

// ---------------------------------------------------------------------------
// Kernel 2: fused split-bf16 MFMA GEMM [64 rows x 192 cols x K=768] +
// row L2-norm + double softmax. 256 threads = 4 waves (2 rg x 2 cg); wave
// owns 32 rows x 96 cols. A: global->reg (no LDS). B: global_load_lds with
// XOR-granule source swizzle; ds_read_b128 with matching swizzle.
// ---------------------------------------------------------------------------
__global__ __launch_bounds__(256, 2) void fused_mfma(
    const float* __restrict__ feat, const unsigned short* __restrict__ PRhi,
    const unsigned short* __restrict__ PRlo, float* __restrict__ out) {
  __shared__ f32x4 smemv[3136];    // 50176 B: 2x24576 B buffers / C tile
  __shared__ float invn[64];
  __shared__ float sarr[576];
  char* smem = (char*)smemv;

  const int t    = threadIdx.x;
  const int lane = t & 63;
  const int wid  = t >> 6;         // 0..3
  const int rg   = wid >> 1;       // rows rg*32..+31
  const int cg   = wid & 1;        // cols cg*96..+95
  const int b0   = blockIdx.x * 64;

  // ---- A: direct global fragment loads. lane -> row (lane&15), k-chunk
  // (lane>>4)*8 floats. Two rowtiles (+0, +16 rows).
  const float* gA0 = feat + (size_t)(b0 + rg * 32 + (lane & 15)) * 768 +
                     ((lane >> 4) << 3);
  const float* gA1 = gA0 + 16 * 768;

  // ---- B DMA: 24 instrs/ktile (2 planes x 12 col-chunks), 6 per wave.
  // lane l covers (local col c=l>>2, slot s=l&3); slot s stores granule
  // g = s ^ ((c>>1)&3)  -> intra-line permutation, stays coalesced.
  const int iid  = wid * 6;
  const int bc   = lane >> 2;                       // local col 0..15
  const int bsw  = (lane & 3) ^ ((bc >> 1) & 3);    // granule to fetch
  // per-lane source offset within a (chunk, ktile): col*1536 + g*16
  const int bsrc = bc * 1536 + bsw * 16;

  // ---- B fragment read offset (swizzled, conflict-free)
  const int bfr = ((lane & 15) << 6) |
                  ((((lane >> 4) ^ (((lane & 15) >> 1) & 3)) & 3) << 4);

  f32x4 acc0[6], acc1[6];
  #pragma unroll
  for (int j = 0; j < 6; ++j) {
    acc0[j] = (f32x4){0.f, 0.f, 0.f, 0.f};
    acc1[j] = (f32x4){0.f, 0.f, 0.f, 0.f};
  }
  float ssq0 = 0.f, ssq1 = 0.f;

  auto issueB = [&](int kt, int bb) {
    #pragma unroll
    for (int u = 0; u < 6; ++u) {
      int i  = iid + u;
      int pl = i >= 12;            // wave-uniform: 0 hi, 1 lo
      int ch = pl ? i - 12 : i;    // col chunk 0..11
      const unsigned short* basep = pl ? PRlo : PRhi;
      const char* gg = (const char*)basep + (size_t)ch * 16 * 1536 +
                       kt * 64 + bsrc;
      char* l = smem + bb * BUF_SZ + (pl ? B_LO_OFF : 0) + ch * 1024 +
                lane * 16;
      __builtin_amdgcn_global_load_lds((const unsigned int*)gg,
                                       (unsigned int*)l, 16, 0, 0);
    }
  };

  float4 ra0a, ra0b, ra1a, ra1b;   // raw A prefetch (8 fp32 per rowtile)
  auto loadA = [&](int kt) {
    ra0a = *(const float4*)(gA0 + kt * 32);
    ra0b = *(const float4*)(gA0 + kt * 32 + 4);
    ra1a = *(const float4*)(gA1 + kt * 32);
    ra1b = *(const float4*)(gA1 + kt * 32 + 4);
  };

  short8 ah0, al0, ah1, al1;
  auto cvtA = [&]() {
    float x0[8] = {ra0a.x, ra0a.y, ra0a.z, ra0a.w, ra0b.x, ra0b.y, ra0b.z, ra0b.w};
    float x1[8] = {ra1a.x, ra1a.y, ra1a.z, ra1a.w, ra1b.x, ra1b.y, ra1b.z, ra1b.w};
    u16x8 h0, l0, h1, l1;
    #pragma unroll
    for (int e = 0; e < 8; ++e) {
      float x = x0[e];
      ssq0 += x * x;
      unsigned int bu = __float_as_uint(x);
      h0[e] = (unsigned short)(bu >> 16);
      l0[e] = (unsigned short)(__float_as_uint(x - __uint_as_float(bu & 0xffff0000u)) >> 16);
      float y = x1[e];
      ssq1 += y * y;
      unsigned int bv = __float_as_uint(y);
      h1[e] = (unsigned short)(bv >> 16);
      l1[e] = (unsigned short)(__float_as_uint(y - __uint_as_float(bv & 0xffff0000u)) >> 16);
    }
    ah0 = (short8)h0; al0 = (short8)l0; ah1 = (short8)h1; al1 = (short8)l1;
  };

  auto domfma = [&](int bb) {
    char* base = smem + bb * BUF_SZ;
    #pragma unroll
    for (int j = 0; j < 6; ++j) {
      int chb = (cg * 6 + j) * 1024;
      short8 bh = *(const short8*)(base + chb + bfr);
      short8 bl = *(const short8*)(base + B_LO_OFF + chb + bfr);
      acc0[j] = __builtin_amdgcn_mfma_f32_16x16x32_bf16(ah0, bh, acc0[j], 0, 0, 0);
      acc0[j] = __builtin_amdgcn_mfma_f32_16x16x32_bf16(al0, bh, acc0[j], 0, 0, 0);
      acc0[j] = __builtin_amdgcn_mfma_f32_16x16x32_bf16(ah0, bl, acc0[j], 0, 0, 0);
      acc1[j] = __builtin_amdgcn_mfma_f32_16x16x32_bf16(ah1, bh, acc1[j], 0, 0, 0);
      acc1[j] = __builtin_amdgcn_mfma_f32_16x16x32_bf16(al1, bh, acc1[j], 0, 0, 0);
      acc1[j] = __builtin_amdgcn_mfma_f32_16x16x32_bf16(ah1, bl, acc1[j], 0, 0, 0);
    }
  };

  // ---- prologue
  loadA(0);
  issueB(0, 0);
  __syncthreads();   // B(0) resident

  // ---- main loop: 2 ktiles/iter (compile-time buffer parity)
  for (int kp = 0; kp < 11; ++kp) {
    int kt = 2 * kp;
    issueB(kt + 1, 1);
    cvtA();
    loadA(kt + 1);
    domfma(0);
    __syncthreads();
    issueB(kt + 2, 0);
    cvtA();
    loadA(kt + 2);
    domfma(1);
    __syncthreads();
  }
  // tail: kt=22 (buf0), kt=23 (buf1)
  issueB(23, 1);
  cvtA();
  loadA(23);
  domfma(0);
  __syncthreads();
  cvtA();
  domfma(1);

  // ---- row L2-norm: lanes l, l+16, l+32, l+48 hold the 4 k-chunk partials
  float v0 = ssq0, v1 = ssq1;
  v0 += __shfl_xor(v0, 16, 64); v0 += __shfl_xor(v0, 32, 64);
  v1 += __shfl_xor(v1, 16, 64); v1 += __shfl_xor(v1, 32, 64);
  if (cg == 0 && lane < 16) {
    invn[rg * 32 + lane]      = rsqrtf(v0);
    invn[rg * 32 + 16 + lane] = rsqrtf(v1);
  }
  __syncthreads();   // invn visible; all MFMA reads done -> smem reusable

  // ---- write scaled C (q|r) to LDS
  float* Clds = (float*)smem;
  #pragma unroll
  for (int rt = 0; rt < 2; ++rt) {
    int rbase = rg * 32 + rt * 16 + ((lane >> 4) << 2);
    #pragma unroll
    for (int j = 0; j < 6; ++j) {
      int col = cg * 96 + j * 16 + (lane & 15);
      f32x4 v = rt ? acc1[j] : acc0[j];
      #pragma unroll
      for (int jj = 0; jj < 4; ++jj)
        Clds[(rbase + jj) * CSTR + col] = v[jj] * invn[rbase + jj];
    }
  }
  __syncthreads();

  // ---- per (row,d): softmax over m, dot with r
  for (int pid = t; pid < 576; pid += 256) {
    int row = pid / 9, d = pid - row * 9;
    const float* qp = Clds + row * CSTR + d * 10;
    const float* rp = qp + 90;
    float mx = qp[0];
    #pragma unroll
    for (int m = 1; m < 10; ++m) mx = fmaxf(mx, qp[m]);
    float s = 0.f, val = 0.f;
    #pragma unroll
    for (int m = 0; m < 10; ++m) {
      float e = __expf(TAUF * (qp[m] - mx));
      s += e;
      val += e * rp[m];
    }
    sarr[pid] = val / s;
  }
  __syncthreads();

  // ---- per row: softmax over d, write out
  if (t < 64) {
    float v[9];
    #pragma unroll
    for (int d = 0; d < 9; ++d) v[d] = sarr[t * 9 + d];
    float mx = v[0];
    #pragma unroll
    for (int d = 1; d < 9; ++d) mx = fmaxf(mx, v[d]);
    float s = 0.f;
    float e[9];
    #pragma unroll
    for (int d = 0; d < 9; ++d) {
      e[d] = __expf(TAUF * (v[d] - mx));
      s += e[d];
    }
    float is = 1.f / s;
    #pragma unroll
    for (int d = 0; d < 9; ++d)
      out[(size_t)(b0 + t) * 9 + d] = e[d] * is;
  }
}

extern "C" void kernel_launch(void* const* d_in, const int* in_sizes, int n_in,
                              void* d_out, int out_size, void* d_ws, size_t ws_size,
                              hipStream_t stream) {
  const float* feat = (const float*)d_in[0];
  // d_in[1] = category (unused by forward math)
  const float* Wt  = (const float*)d_in[2];
  const float* Wd  = (const float*)d_in[3];
  const float* mem = (const float*)d_in[4];
  float* outp = (float*)d_out;

  unsigned short* PRhi = (unsigned short*)d_ws;   // [192][768] bf16
  unsigned short* PRlo = PRhi + 192 * 768;        // [192][768] bf16

  precompute_pr<<<96, 768, 0, stream>>>(Wt, Wd, mem, PRhi, PRlo);
  const int B = in_sizes[1];   // 32768
  fused_mfma<<<B / 64, 256, 0, stream>>>(feat, PRhi, PRlo, outp);
}